// Round 12
// baseline (288.226 us; speedup 1.0000x reference)
//
#include <hip/hip_runtime.h>

#define N_NODES 8192
#define DIM 32
#define NCLS 16
#define SPLITC 64               /* Cpart splits: 16 k-supertiles x 4 waves */
#define NCOLC 36                /* packed partial-C columns (36..47 structurally zero) */
#define PITCH 520               /* LDS row pitch in bf16 elems (1040B, 16B-aligned) */

typedef __bf16 bf16x8 __attribute__((ext_vector_type(8)));
typedef float f32x4 __attribute__((ext_vector_type(4)));

__device__ inline unsigned short f2bf(float f) {
  unsigned u = __float_as_uint(f);
  u = u + 0x7FFFu + ((u >> 16) & 1u);  // RNE
  return (unsigned short)(u >> 16);
}

__device__ inline float artanh_pos(float x) {  // x >= 0, clipped like jnp reference
  x = fminf(x, 1.0f - 1e-7f);
  return 0.5f * logf((1.0f + x) / (1.0f - x));
}

// ---- fragment-linear tile indexing (B-operand tiles) ----
// G: [nt][3 colblk][16 col][32 n]
__device__ inline size_t g_tile_idx(int c, int n) {
  return ((size_t)(n >> 5) * 3 + (c >> 4)) * 512 + (size_t)((c & 15) * 32 + (n & 31));
}
// L: [nt][16 col][32 n]
__device__ inline size_t l_tile_idx(int c, int n) {
  return (size_t)(n >> 5) * 512 + (size_t)(c * 32 + (n & 31));
}

// ---------------- A-pass: read-only fp32 A -> LDS convert/transpose -> MFMA ----------------
// One block = one supertile (16 rows x 512 k). NO bf16 A materialization, NO write
// stream (read-only regime). One barrier total; per-wave Cpart split (ks*4+w).
template <int NF>
__global__ __launch_bounds__(256) void k_mmA(const float* __restrict__ A,
                                             const unsigned short* __restrict__ BT,
                                             float* __restrict__ Cpart) {
  __shared__ __align__(16) unsigned short lds_t[16 * PITCH];  // 16,640 B
  const int t = threadIdx.x;
  const int st = blockIdx.x;
  const int rt = st >> 4;  // row-tile (16 rows)
  const int ks = st & 15;  // k-supertile (512 k)
  const int lane = t & 63;
  const int w = t >> 6;
  const int lr = lane & 15;
  const int lkg = lane >> 4;

  // ph1: 8 dense 1KB-per-instruction NT reads staged to regs (8-deep in flight),
  // then convert + contiguous LDS writes
  const float* src = A + (size_t)(rt * 16) * N_NODES + ks * 512;
  f32x4 r[8];
#pragma unroll
  for (int v = 0; v < 8; v++) {
    const int row = 2 * v + (t >> 7);
    const int k = (t & 127) * 4;
    r[v] = __builtin_nontemporal_load((const f32x4*)(src + (size_t)row * N_NODES + k));
  }
#pragma unroll
  for (int v = 0; v < 8; v++) {
    const int row = 2 * v + (t >> 7);
    const int k = (t & 127) * 4;
    uint2 o;
    o.x = f2bf(r[v][0]) | ((unsigned)f2bf(r[v][1]) << 16);
    o.y = f2bf(r[v][2]) | ((unsigned)f2bf(r[v][3]) << 16);
    *(uint2*)(lds_t + row * PITCH + k) = o;
  }
  __syncthreads();

  // ph2: MFMA — wave w owns local k-tiles 4w..4w+3 (K=128), NF col-blocks
  f32x4 acc[NF];
#pragma unroll
  for (int nf = 0; nf < NF; nf++) acc[nf] = (f32x4){0.f, 0.f, 0.f, 0.f};
  const int poff = lr * 32 + lkg * 8;
#pragma unroll
  for (int i = 0; i < 4; i++) {
    const int kt2 = 4 * w + i;
    bf16x8 a = *(const bf16x8*)(lds_t + lr * PITCH + kt2 * 32 + lkg * 8);
#pragma unroll
    for (int nf = 0; nf < NF; nf++) {
      bf16x8 b = *(const bf16x8*)(BT + ((size_t)(ks * 16 + kt2) * NF + nf) * 512 + poff);
      acc[nf] = __builtin_amdgcn_mfma_f32_16x16x32_bf16(a, b, acc[nf], 0, 0, 0);
    }
  }

  // per-wave Cpart store: split = ks*4 + w (no LDS reduce, no extra barriers)
  const int NCOL = (NF == 3) ? NCOLC : 16;
  float* Cb = Cpart + (size_t)(ks * 4 + w) * N_NODES * NCOL;
#pragma unroll
  for (int nf = 0; nf < NF; nf++) {
    if (NF == 3 && nf == 2 && lr >= 4) continue;  // cols 36..47 never read
#pragma unroll
    for (int j = 0; j < 4; j++) {
      const int row = rt * 16 + lkg * 4 + j;
      const int col = nf * 16 + lr;
      Cb[(size_t)row * NCOL + col] = acc[nf][j];
    }
  }
}

// ---------------- pre: mobius_matvec + gamma -> G tiles ----------------
__device__ inline void pre_math(const float* __restrict__ Wl, const float x[DIM],
                                unsigned short* __restrict__ GT, int n) {
  float xn2 = 0.f;
#pragma unroll
  for (int i = 0; i < DIM; i++) xn2 += x[i] * x[i];
  float xn = sqrtf(fmaxf(xn2, 1e-30f));
  float mx[DIM];
#pragma unroll
  for (int j = 0; j < DIM; j++) mx[j] = 0.f;
  for (int i = 0; i < DIM; i++) {
    float xi = x[i];
#pragma unroll
    for (int j = 0; j < DIM; j++) mx[j] = fmaf(xi, Wl[i * DIM + j], mx[j]);
  }
  float mxn2 = 0.f;
#pragma unroll
  for (int j = 0; j < DIM; j++) mxn2 += mx[j] * mx[j];
  float mxn = sqrtf(fmaxf(mxn2, 1e-30f));
  float t = tanhf(mxn / xn * artanh_pos(xn));
  float sc = t / mxn;
  float xw[DIM];
  float x2n = 0.f;
#pragma unroll
  for (int j = 0; j < DIM; j++) { xw[j] = sc * mx[j]; x2n += xw[j] * xw[j]; }
  float gamma = 2.0f / fmaxf(1.0f - x2n, 1e-15f);
#pragma unroll
  for (int c = 0; c < DIM; c++) GT[g_tile_idx(c, n)] = f2bf(gamma * xw[c]);
  GT[g_tile_idx(32, n)] = f2bf(gamma - 1.0f);
  GT[g_tile_idx(33, n)] = f2bf(1.0f);
#pragma unroll
  for (int c = DIM + 2; c < 48; c++) GT[g_tile_idx(c, n)] = 0;
}

__global__ void k_pre1(const float* __restrict__ X, const float* __restrict__ W,
                       unsigned short* __restrict__ GT) {
  __shared__ float Wl[DIM * DIM];
  for (int i = threadIdx.x; i < DIM * DIM; i += blockDim.x) Wl[i] = W[i];
  __syncthreads();
  const int n = blockIdx.x * blockDim.x + threadIdx.x;
  float x[DIM];
#pragma unroll
  for (int i = 0; i < DIM; i += 4) {
    float4 v = *(const float4*)(X + (size_t)n * DIM + i);
    x[i] = v.x; x[i + 1] = v.y; x[i + 2] = v.z; x[i + 3] = v.w;
  }
  pre_math(Wl, x, GT, n);
}

// ---------------- post math: reduces Cpart's 64 splits directly ----------------
__device__ inline void post_math(const float* __restrict__ Cpart, int n, float xo[DIM]) {
  float acc[NCOLC];
#pragma unroll
  for (int c = 0; c < NCOLC; c++) acc[c] = 0.f;
  for (int s = 0; s < SPLITC; s++) {
    const float4* p = (const float4*)(Cpart + ((size_t)s * N_NODES + n) * NCOLC);
#pragma unroll
    for (int q = 0; q < NCOLC / 4; q++) {
      float4 v = p[q];
      acc[q * 4 + 0] += v.x; acc[q * 4 + 1] += v.y;
      acc[q * 4 + 2] += v.z; acc[q * 4 + 3] += v.w;
    }
  }
  float denom = acc[32];
  float alpha = acc[33];
  denom = (denom >= 0.f) ? fmaxf(denom, 1e-10f) : fminf(denom, -1e-10f);
  float inv = 1.0f / denom;
  float v[DIM];
  float vn2 = 0.f;
#pragma unroll
  for (int c = 0; c < DIM; c++) { v[c] = acc[c] * inv; vn2 += v[c] * v[c]; }
  float vn = sqrtf(fmaxf(vn2, 1e-30f));
  float un = alpha * 0.5f * artanh_pos(vn);
  float su = un / vn;
  float r[DIM];
  float rn2 = 0.f;
#pragma unroll
  for (int c = 0; c < DIM; c++) { r[c] = fmaxf(su * v[c], 0.f); rn2 += r[c] * r[c]; }
  float rn = sqrtf(fmaxf(rn2, 1e-30f));
  float so = tanhf(rn) / rn;
#pragma unroll
  for (int c = 0; c < DIM; c++) xo[c] = so * r[c];
}

__global__ void k_postpre(const float* __restrict__ Cpart, const float* __restrict__ W,
                          unsigned short* __restrict__ GT) {
  __shared__ float Wl[DIM * DIM];
  for (int i = threadIdx.x; i < DIM * DIM; i += blockDim.x) Wl[i] = W[i];
  __syncthreads();
  const int n = blockIdx.x * blockDim.x + threadIdx.x;
  float x[DIM];
  post_math(Cpart, n, x);
  pre_math(Wl, x, GT, n);
}

__global__ void k_postlogits(const float* __restrict__ Cpart, const float* __restrict__ Wl_g,
                             const float* __restrict__ B_g, unsigned short* __restrict__ LT) {
  __shared__ float Wc[DIM * NCLS];
  __shared__ float Bc[NCLS * DIM];
  __shared__ float an_s[NCLS], lam_s[NCLS], b2_s[NCLS];
  for (int i = threadIdx.x; i < DIM * NCLS; i += blockDim.x) { Wc[i] = Wl_g[i]; Bc[i] = B_g[i]; }
  __syncthreads();
  if (threadIdx.x < NCLS) {
    int c = threadIdx.x;
    float b2 = 0.f, w2 = 0.f;
    for (int d = 0; d < DIM; d++) {
      b2 += Bc[c * DIM + d] * Bc[c * DIM + d];
      w2 += Wc[d * NCLS + c] * Wc[d * NCLS + c];
    }
    b2_s[c] = b2;
    an_s[c] = fmaxf(sqrtf(w2), 1e-10f);
    lam_s[c] = 2.0f / fmaxf(1.0f - b2, 1e-15f);
  }
  __syncthreads();
  const int n = blockIdx.x * blockDim.x + threadIdx.x;
  float x[DIM];
  post_math(Cpart, n, x);
  float y2 = 0.f;
#pragma unroll
  for (int i = 0; i < DIM; i++) y2 += x[i] * x[i];
  for (int c = 0; c < NCLS; c++) {
    float b2 = b2_s[c];
    float bx = 0.f;
    for (int d = 0; d < DIM; d++) bx += Bc[c * DIM + d] * x[d];
    float xy = -bx;
    float f1 = 1.0f + 2.0f * xy + y2;
    float f2 = 1.0f - b2;
    float den = fmaxf(1.0f + 2.0f * xy + b2 * y2, 1e-15f);
    float invden = 1.0f / den;
    float zn2 = 0.f, za = 0.f;
    for (int d = 0; d < DIM; d++) {
      float z = (f1 * (-Bc[c * DIM + d]) + f2 * x[d]) * invden;
      zn2 += z * z;
      za += z * Wc[d * NCLS + c];
    }
    float zn = fmaxf(sqrtf(fmaxf(zn2, 1e-30f)), 1e-10f);
    float dist = asinhf(2.0f * za / ((1.0f - zn * zn) * an_s[c]));
    LT[l_tile_idx(c, n)] = f2bf(lam_s[c] * an_s[c] * dist);
  }
}

// ---------------- final splitK reduce into d_out ----------------
template <int TOTAL>
__global__ void k_red(const float* __restrict__ part, float* __restrict__ outb) {
  int i = blockIdx.x * blockDim.x + threadIdx.x;
  if (i < TOTAL) {
    float s = 0.f;
#pragma unroll
    for (int q = 0; q < SPLITC; q++) s += part[(size_t)q * TOTAL + i];
    outb[i] = s;
  }
}

extern "C" void kernel_launch(void* const* d_in, const int* in_sizes, int n_in,
                              void* d_out, int out_size, void* d_ws, size_t ws_size,
                              hipStream_t stream) {
  (void)in_sizes; (void)n_in; (void)out_size; (void)ws_size;
  const float* X  = (const float*)d_in[0];
  const float* A  = (const float*)d_in[1];
  const float* W1 = (const float*)d_in[2];
  const float* W2 = (const float*)d_in[3];
  const float* WL = (const float*)d_in[4];
  const float* PK = (const float*)d_in[5];
  float* out = (float*)d_out;

  char* ws = (char*)d_ws;
  unsigned short* GT = (unsigned short*)ws;              //    786,432 B (tiled)
  unsigned short* LT = (unsigned short*)(ws + 786432);   //    262,144 B (tiled)
  float* Cpart       = (float*)(ws + 1048576);           // 75,497,472 B (64 splits x 36 cols)

  // layer 1
  k_pre1<<<N_NODES / 64, 64, 0, stream>>>(X, W1, GT);
  k_mmA<3><<<8192, 256, 0, stream>>>(A, GT, Cpart);
  k_postpre<<<N_NODES / 64, 64, 0, stream>>>(Cpart, W2, GT);

  // layer 2
  k_mmA<3><<<8192, 256, 0, stream>>>(A, GT, Cpart);
  k_postlogits<<<N_NODES / 64, 64, 0, stream>>>(Cpart, WL, PK, LT);

  // logits aggregation
  k_mmA<1><<<8192, 256, 0, stream>>>(A, LT, Cpart);
  k_red<N_NODES * NCLS><<<(N_NODES * NCLS + 255) / 256, 256, 0, stream>>>(Cpart, out);
}

// Round 13
// 181.288 us; speedup vs baseline: 1.5899x; 1.5899x over previous
//
#include <hip/hip_runtime.h>

#define N_NODES 8192
#define DIM 32
#define NCLS 16
#define NCOLC 36                /* packed partial-C columns (36..47 structurally zero) */
#define NKT (N_NODES / 32)      /* 256 k-tiles per row stripe */
#define RT_STRIDE ((size_t)NKT * 512)
#define PITCH 520               /* LDS row pitch in bf16 elems (1040B) */
#define KSEG 512                /* k per supertile */

typedef __bf16 bf16x8 __attribute__((ext_vector_type(8)));
typedef float f32x4 __attribute__((ext_vector_type(4)));

__device__ inline unsigned short f2bf(float f) {
  unsigned u = __float_as_uint(f);
  u = u + 0x7FFFu + ((u >> 16) & 1u);  // RNE
  return (unsigned short)(u >> 16);
}

__device__ inline float artanh_pos(float x) {
  x = fminf(x, 1.0f - 1e-7f);
  return 0.5f * logf((1.0f + x) / (1.0f - x));
}

// G: [nt][3 colblk][16 col][32 n]
__device__ inline size_t g_tile_idx(int c, int n) {
  return ((size_t)(n >> 5) * 3 + (c >> 4)) * 512 + (size_t)((c & 15) * 32 + (n & 31));
}
// L: [nt][16 col][32 n]
__device__ inline size_t l_tile_idx(int c, int n) {
  return (size_t)(n >> 5) * 512 + (size_t)(c * 32 + (n & 31));
}

// ---------------- FUSED pipelined: A fp32 -> bf16 tiles + mm pass 1 ----------------
// One block = one row-tile x TWO k-supertiles (S0=2q, S1=2q+1), double-buffered LDS.
// S1's global loads are issued BEFORE S0's compute -> HBM reads stay in flight
// under MFMA/store (T14 reg-staged async split). acc accumulates across both
// supertiles -> Cpart has only 8 splits.
__global__ __launch_bounds__(256) void k_mmc(const float* __restrict__ A,
                                             const unsigned short* __restrict__ GT,
                                             unsigned short* __restrict__ Abf,
                                             float* __restrict__ Cpart) {
  __shared__ __align__(16) unsigned short buf0[16 * PITCH];  // 16,640 B
  __shared__ __align__(16) unsigned short buf1[16 * PITCH];  // 16,640 B
  float* lds_r = (float*)buf0;  // reused for reduce (12,288 B needed)
  const int t = threadIdx.x;
  const int rt = blockIdx.x >> 3;  // row-tile (16 rows)
  const int q = blockIdx.x & 7;    // supertile pair -> split index
  const int ks0 = 2 * q, ks1 = 2 * q + 1;
  const int lane = t & 63;
  const int w = t >> 6;
  const int lr = lane & 15;
  const int lkg = lane >> 4;
  const int vrow = t >> 7;          // staging row parity
  const int vk = (t & 127) * 4;     // staging k offset
  const int poff = lr * 32 + lkg * 8;

  const float* srcbase = A + (size_t)(rt * 16) * N_NODES;

  // S0 loads -> regs -> LDS buf0
  f32x4 r0[8];
#pragma unroll
  for (int v = 0; v < 8; v++)
    r0[v] = __builtin_nontemporal_load(
        (const f32x4*)(srcbase + (size_t)(2 * v + vrow) * N_NODES + ks0 * KSEG + vk));
#pragma unroll
  for (int v = 0; v < 8; v++) {
    uint2 o;
    o.x = f2bf(r0[v][0]) | ((unsigned)f2bf(r0[v][1]) << 16);
    o.y = f2bf(r0[v][2]) | ((unsigned)f2bf(r0[v][3]) << 16);
    *(uint2*)(buf0 + (2 * v + vrow) * PITCH + vk) = o;
  }
  __syncthreads();

  // issue S1 loads NOW (in flight under S0 compute)
  f32x4 r1[8];
#pragma unroll
  for (int v = 0; v < 8; v++)
    r1[v] = __builtin_nontemporal_load(
        (const f32x4*)(srcbase + (size_t)(2 * v + vrow) * N_NODES + ks1 * KSEG + vk));

  // MFMA S0: wave w owns local k-tiles 4w..4w+3
  f32x4 acc[3];
#pragma unroll
  for (int nf = 0; nf < 3; nf++) acc[nf] = (f32x4){0.f, 0.f, 0.f, 0.f};
#pragma unroll
  for (int i = 0; i < 4; i++) {
    const int kt2 = 4 * w + i;
    bf16x8 a = *(const bf16x8*)(buf0 + lr * PITCH + kt2 * 32 + lkg * 8);
#pragma unroll
    for (int nf = 0; nf < 3; nf++) {
      bf16x8 b = *(const bf16x8*)(GT + ((size_t)(ks0 * 16 + kt2) * 3 + nf) * 512 + poff);
      acc[nf] = __builtin_amdgcn_mfma_f32_16x16x32_bf16(a, b, acc[nf], 0, 0, 0);
    }
  }
  // Abf store S0 (dense contiguous 16KB supertile)
  {
    unsigned short* dst = Abf + (size_t)(rt * 16 + ks0) * 8192;
#pragma unroll
    for (int u = 0; u < 4; u++) {
      const int p = u * 256 + t;
      const int kt = p >> 6;
      const int qq = p & 63;
      bf16x8 val = *(const bf16x8*)(buf0 + (qq >> 2) * PITCH + kt * 32 + (qq & 3) * 8);
      *(bf16x8*)(dst + (size_t)p * 8) = val;
    }
  }

  // stage S1 into buf1 (vmcnt wait inserted here by compiler), then sync
#pragma unroll
  for (int v = 0; v < 8; v++) {
    uint2 o;
    o.x = f2bf(r1[v][0]) | ((unsigned)f2bf(r1[v][1]) << 16);
    o.y = f2bf(r1[v][2]) | ((unsigned)f2bf(r1[v][3]) << 16);
    *(uint2*)(buf1 + (2 * v + vrow) * PITCH + vk) = o;
  }
  __syncthreads();

  // MFMA S1 (accumulate into same acc)
#pragma unroll
  for (int i = 0; i < 4; i++) {
    const int kt2 = 4 * w + i;
    bf16x8 a = *(const bf16x8*)(buf1 + lr * PITCH + kt2 * 32 + lkg * 8);
#pragma unroll
    for (int nf = 0; nf < 3; nf++) {
      bf16x8 b = *(const bf16x8*)(GT + ((size_t)(ks1 * 16 + kt2) * 3 + nf) * 512 + poff);
      acc[nf] = __builtin_amdgcn_mfma_f32_16x16x32_bf16(a, b, acc[nf], 0, 0, 0);
    }
  }
  // Abf store S1
  {
    unsigned short* dst = Abf + (size_t)(rt * 16 + ks1) * 8192;
#pragma unroll
    for (int u = 0; u < 4; u++) {
      const int p = u * 256 + t;
      const int kt = p >> 6;
      const int qq = p & 63;
      bf16x8 val = *(const bf16x8*)(buf1 + (qq >> 2) * PITCH + kt * 32 + (qq & 3) * 8);
      *(bf16x8*)(dst + (size_t)p * 8) = val;
    }
  }
  __syncthreads();  // buf0 dead (all S0 reads done before 2nd barrier)

  // 4-wave reduce via lds_r (=buf0): dump
#pragma unroll
  for (int nf = 0; nf < 3; nf++)
#pragma unroll
    for (int j = 0; j < 4; j++)
      lds_r[(w * 16 + lkg * 4 + j) * 48 + nf * 16 + lr] = acc[nf][j];
  __syncthreads();
  for (int e = t; e < 16 * 36; e += 256) {
    const int row = e / 36;
    const int col = e % 36;
    float s = lds_r[row * 48 + col] + lds_r[768 + row * 48 + col] +
              lds_r[1536 + row * 48 + col] + lds_r[2304 + row * 48 + col];
    Cpart[((size_t)q * N_NODES + rt * 16 + row) * NCOLC + col] = s;
  }
}

// ---------------- pre: mobius_matvec + gamma -> G tiles ----------------
__device__ inline void pre_math(const float* __restrict__ Wl, const float x[DIM],
                                unsigned short* __restrict__ GT, int n) {
  float xn2 = 0.f;
#pragma unroll
  for (int i = 0; i < DIM; i++) xn2 += x[i] * x[i];
  float xn = sqrtf(fmaxf(xn2, 1e-30f));
  float mx[DIM];
#pragma unroll
  for (int j = 0; j < DIM; j++) mx[j] = 0.f;
  for (int i = 0; i < DIM; i++) {
    float xi = x[i];
#pragma unroll
    for (int j = 0; j < DIM; j++) mx[j] = fmaf(xi, Wl[i * DIM + j], mx[j]);
  }
  float mxn2 = 0.f;
#pragma unroll
  for (int j = 0; j < DIM; j++) mxn2 += mx[j] * mx[j];
  float mxn = sqrtf(fmaxf(mxn2, 1e-30f));
  float t = tanhf(mxn / xn * artanh_pos(xn));
  float sc = t / mxn;
  float xw[DIM];
  float x2n = 0.f;
#pragma unroll
  for (int j = 0; j < DIM; j++) { xw[j] = sc * mx[j]; x2n += xw[j] * xw[j]; }
  float gamma = 2.0f / fmaxf(1.0f - x2n, 1e-15f);
#pragma unroll
  for (int c = 0; c < DIM; c++) GT[g_tile_idx(c, n)] = f2bf(gamma * xw[c]);
  GT[g_tile_idx(32, n)] = f2bf(gamma - 1.0f);
  GT[g_tile_idx(33, n)] = f2bf(1.0f);
#pragma unroll
  for (int c = DIM + 2; c < 48; c++) GT[g_tile_idx(c, n)] = 0;
}

__global__ void k_pre1(const float* __restrict__ X, const float* __restrict__ W,
                       unsigned short* __restrict__ GT) {
  __shared__ float Wl[DIM * DIM];
  for (int i = threadIdx.x; i < DIM * DIM; i += blockDim.x) Wl[i] = W[i];
  __syncthreads();
  const int n = blockIdx.x * blockDim.x + threadIdx.x;
  float x[DIM];
#pragma unroll
  for (int i = 0; i < DIM; i += 4) {
    float4 v = *(const float4*)(X + (size_t)n * DIM + i);
    x[i] = v.x; x[i + 1] = v.y; x[i + 2] = v.z; x[i + 3] = v.w;
  }
  pre_math(Wl, x, GT, n);
}

// ---------------- post math: reduces SPLITS partial blocks ----------------
template <int SPLITS>
__device__ inline void post_math(const float* __restrict__ Cpart, int n, float xo[DIM]) {
  float acc[NCOLC];
#pragma unroll
  for (int c = 0; c < NCOLC; c++) acc[c] = 0.f;
  for (int s = 0; s < SPLITS; s++) {
    const float4* p = (const float4*)(Cpart + ((size_t)s * N_NODES + n) * NCOLC);
#pragma unroll
    for (int qq = 0; qq < NCOLC / 4; qq++) {
      float4 v = p[qq];
      acc[qq * 4 + 0] += v.x; acc[qq * 4 + 1] += v.y;
      acc[qq * 4 + 2] += v.z; acc[qq * 4 + 3] += v.w;
    }
  }
  float denom = acc[32];
  float alpha = acc[33];
  denom = (denom >= 0.f) ? fmaxf(denom, 1e-10f) : fminf(denom, -1e-10f);
  float inv = 1.0f / denom;
  float v[DIM];
  float vn2 = 0.f;
#pragma unroll
  for (int c = 0; c < DIM; c++) { v[c] = acc[c] * inv; vn2 += v[c] * v[c]; }
  float vn = sqrtf(fmaxf(vn2, 1e-30f));
  float un = alpha * 0.5f * artanh_pos(vn);
  float su = un / vn;
  float r[DIM];
  float rn2 = 0.f;
#pragma unroll
  for (int c = 0; c < DIM; c++) { r[c] = fmaxf(su * v[c], 0.f); rn2 += r[c] * r[c]; }
  float rn = sqrtf(fmaxf(rn2, 1e-30f));
  float so = tanhf(rn) / rn;
#pragma unroll
  for (int c = 0; c < DIM; c++) xo[c] = so * r[c];
}

__global__ void k_postpre(const float* __restrict__ Cpart, const float* __restrict__ W,
                          unsigned short* __restrict__ GT) {
  __shared__ float Wl[DIM * DIM];
  for (int i = threadIdx.x; i < DIM * DIM; i += blockDim.x) Wl[i] = W[i];
  __syncthreads();
  const int n = blockIdx.x * blockDim.x + threadIdx.x;
  float x[DIM];
  post_math<8>(Cpart, n, x);
  pre_math(Wl, x, GT, n);
}

__global__ void k_postlogits(const float* __restrict__ Cpart, const float* __restrict__ Wl_g,
                             const float* __restrict__ B_g, unsigned short* __restrict__ LT) {
  __shared__ float Wc[DIM * NCLS];
  __shared__ float Bc[NCLS * DIM];
  __shared__ float an_s[NCLS], lam_s[NCLS], b2_s[NCLS];
  for (int i = threadIdx.x; i < DIM * NCLS; i += blockDim.x) { Wc[i] = Wl_g[i]; Bc[i] = B_g[i]; }
  __syncthreads();
  if (threadIdx.x < NCLS) {
    int c = threadIdx.x;
    float b2 = 0.f, w2 = 0.f;
    for (int d = 0; d < DIM; d++) {
      b2 += Bc[c * DIM + d] * Bc[c * DIM + d];
      w2 += Wc[d * NCLS + c] * Wc[d * NCLS + c];
    }
    b2_s[c] = b2;
    an_s[c] = fmaxf(sqrtf(w2), 1e-10f);
    lam_s[c] = 2.0f / fmaxf(1.0f - b2, 1e-15f);
  }
  __syncthreads();
  const int n = blockIdx.x * blockDim.x + threadIdx.x;
  float x[DIM];
  post_math<16>(Cpart, n, x);
  float y2 = 0.f;
#pragma unroll
  for (int i = 0; i < DIM; i++) y2 += x[i] * x[i];
  for (int c = 0; c < NCLS; c++) {
    float b2 = b2_s[c];
    float bx = 0.f;
    for (int d = 0; d < DIM; d++) bx += Bc[c * DIM + d] * x[d];
    float xy = -bx;
    float f1 = 1.0f + 2.0f * xy + y2;
    float f2 = 1.0f - b2;
    float den = fmaxf(1.0f + 2.0f * xy + b2 * y2, 1e-15f);
    float invden = 1.0f / den;
    float zn2 = 0.f, za = 0.f;
    for (int d = 0; d < DIM; d++) {
      float z = (f1 * (-Bc[c * DIM + d]) + f2 * x[d]) * invden;
      zn2 += z * z;
      za += z * Wc[d * NCLS + c];
    }
    float zn = fmaxf(sqrtf(fmaxf(zn2, 1e-30f)), 1e-10f);
    float dist = asinhf(2.0f * za / ((1.0f - zn * zn) * an_s[c]));
    LT[l_tile_idx(c, n)] = f2bf(lam_s[c] * an_s[c] * dist);
  }
}

// ---------------- MFMA matmul over fragment-linear Abf tiles (passes 2/3) ----------------
template <int NF>
__global__ __launch_bounds__(256) void k_mm(const unsigned short* __restrict__ A,
                                            const unsigned short* __restrict__ BT,
                                            float* __restrict__ Cpart) {
  const int lane = threadIdx.x & 63;
  const int wid = threadIdx.x >> 6;
  const int r0 = blockIdx.x * 128 + wid * 32;
  const int kt0 = blockIdx.y * (512 / 32);
  const int lr = lane & 15;
  const int lkg = lane >> 4;
  const int poff = lr * 32 + lkg * 8;
  const int BS = (NF == 3) ? 3 : 1;
  f32x4 acc[2][NF];
#pragma unroll
  for (int m = 0; m < 2; m++)
#pragma unroll
    for (int nf = 0; nf < NF; nf++) acc[m][nf] = (f32x4){0.f, 0.f, 0.f, 0.f};
  const unsigned short* pa0 = A + ((size_t)(r0 >> 4) * NKT + kt0) * 512 + poff;
  const unsigned short* pa1 = pa0 + RT_STRIDE;
  const unsigned short* pbB = BT + (size_t)kt0 * BS * 512 + poff;
#pragma unroll 4
  for (int kt = 0; kt < 16; kt++) {
    bf16x8 a0 = *(const bf16x8*)(pa0 + (size_t)kt * 512);
    bf16x8 a1 = *(const bf16x8*)(pa1 + (size_t)kt * 512);
#pragma unroll
    for (int nf = 0; nf < NF; nf++) {
      bf16x8 b = *(const bf16x8*)(pbB + (size_t)(kt * BS + nf) * 512);
      acc[0][nf] = __builtin_amdgcn_mfma_f32_16x16x32_bf16(a0, b, acc[0][nf], 0, 0, 0);
      acc[1][nf] = __builtin_amdgcn_mfma_f32_16x16x32_bf16(a1, b, acc[1][nf], 0, 0, 0);
    }
  }
  const int NCOL = (NF == 3) ? NCOLC : NF * 16;
  float* Cb = Cpart + (size_t)blockIdx.y * N_NODES * NCOL;
#pragma unroll
  for (int m = 0; m < 2; m++)
#pragma unroll
    for (int nf = 0; nf < NF; nf++) {
      if (NF == 3 && nf == 2 && lr >= 4) continue;
#pragma unroll
      for (int j = 0; j < 4; j++) {
        int row = r0 + m * 16 + lkg * 4 + j;
        int col = nf * 16 + lr;
        Cb[(size_t)row * NCOL + col] = acc[m][nf][j];
      }
    }
}

// ---------------- final splitK reduce into d_out ----------------
template <int TOTAL, int SPLITS>
__global__ void k_red(const float* __restrict__ part, float* __restrict__ outb) {
  int i = blockIdx.x * blockDim.x + threadIdx.x;
  if (i < TOTAL) {
    float s = 0.f;
#pragma unroll
    for (int qq = 0; qq < SPLITS; qq++) s += part[(size_t)qq * TOTAL + i];
    outb[i] = s;
  }
}

extern "C" void kernel_launch(void* const* d_in, const int* in_sizes, int n_in,
                              void* d_out, int out_size, void* d_ws, size_t ws_size,
                              hipStream_t stream) {
  (void)in_sizes; (void)n_in; (void)out_size; (void)ws_size;
  const float* X  = (const float*)d_in[0];
  const float* A  = (const float*)d_in[1];
  const float* W1 = (const float*)d_in[2];
  const float* W2 = (const float*)d_in[3];
  const float* WL = (const float*)d_in[4];
  const float* PK = (const float*)d_in[5];
  float* out = (float*)d_out;

  char* ws = (char*)d_ws;
  unsigned short* Abf = (unsigned short*)ws;                  // 134,217,728 B (tiled)
  unsigned short* GT  = (unsigned short*)(ws + 134217728);    //     786,432 B (tiled)
  float* Cpart        = (float*)(ws + 135004160);             //  18,874,368 B
  unsigned short* LT  = (unsigned short*)(ws + 153878528);    //     262,144 B (tiled)

  // layer 1: fused pipelined convert + mm1
  k_pre1<<<N_NODES / 64, 64, 0, stream>>>(X, W1, GT);
  k_mmc<<<4096, 256, 0, stream>>>(A, GT, Abf, Cpart);
  k_postpre<<<N_NODES / 64, 64, 0, stream>>>(Cpart, W2, GT);

  // layer 2
  k_mm<3><<<dim3(64, 16), 256, 0, stream>>>(Abf, GT, Cpart);
  k_postlogits<<<N_NODES / 64, 64, 0, stream>>>(Cpart, WL, PK, LT);

  // logits aggregation
  k_mm<1><<<dim3(64, 16), 256, 0, stream>>>(Abf, LT, Cpart);
  k_red<N_NODES * NCLS, 16><<<(N_NODES * NCLS + 255) / 256, 256, 0, stream>>>(Cpart, out);
}

// Round 14
// 175.936 us; speedup vs baseline: 1.6382x; 1.0304x over previous
//
#include <hip/hip_runtime.h>

#define N_NODES 8192
#define DIM 32
#define NCLS 16
#define NCOLC 36                /* packed partial-C columns (36..47 structurally zero) */
#define NKT (N_NODES / 32)      /* 256 k-tiles per row stripe */
#define RT_STRIDE ((size_t)NKT * 512)
#define PITCH 520               /* LDS row pitch in bf16 elems (1040B) */
#define KSEG 512                /* k per supertile (k_mmc) */
#define SPLITS 8                /* Cpart splits for all passes */

typedef __bf16 bf16x8 __attribute__((ext_vector_type(8)));
typedef float f32x4 __attribute__((ext_vector_type(4)));

__device__ inline unsigned short f2bf(float f) {
  unsigned u = __float_as_uint(f);
  u = u + 0x7FFFu + ((u >> 16) & 1u);  // RNE
  return (unsigned short)(u >> 16);
}

__device__ inline float artanh_pos(float x) {
  x = fminf(x, 1.0f - 1e-7f);
  return 0.5f * logf((1.0f + x) / (1.0f - x));
}

// G: [nt][3 colblk][16 col][32 n]
__device__ inline size_t g_tile_idx(int c, int n) {
  return ((size_t)(n >> 5) * 3 + (c >> 4)) * 512 + (size_t)((c & 15) * 32 + (n & 31));
}
// L: [nt][16 col][32 n]
__device__ inline size_t l_tile_idx(int c, int n) {
  return (size_t)(n >> 5) * 512 + (size_t)(c * 32 + (n & 31));
}

// ---------------- FUSED pipelined: A fp32 -> bf16 tiles + mm pass 1 ----------------
// R13 structure; Abf stores are NON-TEMPORAL (straight to HBM, no L3 dirty-line
// writeback interference with the A read stream).
__global__ __launch_bounds__(256) void k_mmc(const float* __restrict__ A,
                                             const unsigned short* __restrict__ GT,
                                             unsigned short* __restrict__ Abf,
                                             float* __restrict__ Cpart) {
  __shared__ __align__(16) unsigned short buf0[16 * PITCH];
  __shared__ __align__(16) unsigned short buf1[16 * PITCH];
  float* lds_r = (float*)buf0;
  const int t = threadIdx.x;
  const int rt = blockIdx.x >> 3;
  const int q = blockIdx.x & 7;
  const int ks0 = 2 * q, ks1 = 2 * q + 1;
  const int lane = t & 63;
  const int w = t >> 6;
  const int lr = lane & 15;
  const int lkg = lane >> 4;
  const int vrow = t >> 7;
  const int vk = (t & 127) * 4;
  const int poff = lr * 32 + lkg * 8;

  const float* srcbase = A + (size_t)(rt * 16) * N_NODES;

  f32x4 r0[8];
#pragma unroll
  for (int v = 0; v < 8; v++)
    r0[v] = __builtin_nontemporal_load(
        (const f32x4*)(srcbase + (size_t)(2 * v + vrow) * N_NODES + ks0 * KSEG + vk));
#pragma unroll
  for (int v = 0; v < 8; v++) {
    uint2 o;
    o.x = f2bf(r0[v][0]) | ((unsigned)f2bf(r0[v][1]) << 16);
    o.y = f2bf(r0[v][2]) | ((unsigned)f2bf(r0[v][3]) << 16);
    *(uint2*)(buf0 + (2 * v + vrow) * PITCH + vk) = o;
  }
  __syncthreads();

  f32x4 r1[8];
#pragma unroll
  for (int v = 0; v < 8; v++)
    r1[v] = __builtin_nontemporal_load(
        (const f32x4*)(srcbase + (size_t)(2 * v + vrow) * N_NODES + ks1 * KSEG + vk));

  f32x4 acc[3];
#pragma unroll
  for (int nf = 0; nf < 3; nf++) acc[nf] = (f32x4){0.f, 0.f, 0.f, 0.f};
#pragma unroll
  for (int i = 0; i < 4; i++) {
    const int kt2 = 4 * w + i;
    bf16x8 a = *(const bf16x8*)(buf0 + lr * PITCH + kt2 * 32 + lkg * 8);
#pragma unroll
    for (int nf = 0; nf < 3; nf++) {
      bf16x8 b = *(const bf16x8*)(GT + ((size_t)(ks0 * 16 + kt2) * 3 + nf) * 512 + poff);
      acc[nf] = __builtin_amdgcn_mfma_f32_16x16x32_bf16(a, b, acc[nf], 0, 0, 0);
    }
  }
  {
    unsigned short* dst = Abf + (size_t)(rt * 16 + ks0) * 8192;
#pragma unroll
    for (int u = 0; u < 4; u++) {
      const int p = u * 256 + t;
      const int kt = p >> 6;
      const int qq = p & 63;
      bf16x8 val = *(const bf16x8*)(buf0 + (qq >> 2) * PITCH + kt * 32 + (qq & 3) * 8);
      __builtin_nontemporal_store(val, (bf16x8*)(dst + (size_t)p * 8));
    }
  }

#pragma unroll
  for (int v = 0; v < 8; v++) {
    uint2 o;
    o.x = f2bf(r1[v][0]) | ((unsigned)f2bf(r1[v][1]) << 16);
    o.y = f2bf(r1[v][2]) | ((unsigned)f2bf(r1[v][3]) << 16);
    *(uint2*)(buf1 + (2 * v + vrow) * PITCH + vk) = o;
  }
  __syncthreads();

#pragma unroll
  for (int i = 0; i < 4; i++) {
    const int kt2 = 4 * w + i;
    bf16x8 a = *(const bf16x8*)(buf1 + lr * PITCH + kt2 * 32 + lkg * 8);
#pragma unroll
    for (int nf = 0; nf < 3; nf++) {
      bf16x8 b = *(const bf16x8*)(GT + ((size_t)(ks1 * 16 + kt2) * 3 + nf) * 512 + poff);
      acc[nf] = __builtin_amdgcn_mfma_f32_16x16x32_bf16(a, b, acc[nf], 0, 0, 0);
    }
  }
  {
    unsigned short* dst = Abf + (size_t)(rt * 16 + ks1) * 8192;
#pragma unroll
    for (int u = 0; u < 4; u++) {
      const int p = u * 256 + t;
      const int kt = p >> 6;
      const int qq = p & 63;
      bf16x8 val = *(const bf16x8*)(buf1 + (qq >> 2) * PITCH + kt * 32 + (qq & 3) * 8);
      __builtin_nontemporal_store(val, (bf16x8*)(dst + (size_t)p * 8));
    }
  }
  __syncthreads();

#pragma unroll
  for (int nf = 0; nf < 3; nf++)
#pragma unroll
    for (int j = 0; j < 4; j++)
      lds_r[(w * 16 + lkg * 4 + j) * 48 + nf * 16 + lr] = acc[nf][j];
  __syncthreads();
  for (int e = t; e < 16 * 36; e += 256) {
    const int row = e / 36;
    const int col = e % 36;
    float s = lds_r[row * 48 + col] + lds_r[768 + row * 48 + col] +
              lds_r[1536 + row * 48 + col] + lds_r[2304 + row * 48 + col];
    Cpart[((size_t)q * N_NODES + rt * 16 + row) * NCOLC + col] = s;
  }
}

// ---------------- pre: mobius_matvec + gamma -> G tiles ----------------
__device__ inline void pre_math(const float* __restrict__ Wl, const float x[DIM],
                                unsigned short* __restrict__ GT, int n) {
  float xn2 = 0.f;
#pragma unroll
  for (int i = 0; i < DIM; i++) xn2 += x[i] * x[i];
  float xn = sqrtf(fmaxf(xn2, 1e-30f));
  float mx[DIM];
#pragma unroll
  for (int j = 0; j < DIM; j++) mx[j] = 0.f;
  for (int i = 0; i < DIM; i++) {
    float xi = x[i];
#pragma unroll
    for (int j = 0; j < DIM; j++) mx[j] = fmaf(xi, Wl[i * DIM + j], mx[j]);
  }
  float mxn2 = 0.f;
#pragma unroll
  for (int j = 0; j < DIM; j++) mxn2 += mx[j] * mx[j];
  float mxn = sqrtf(fmaxf(mxn2, 1e-30f));
  float t = tanhf(mxn / xn * artanh_pos(xn));
  float sc = t / mxn;
  float xw[DIM];
  float x2n = 0.f;
#pragma unroll
  for (int j = 0; j < DIM; j++) { xw[j] = sc * mx[j]; x2n += xw[j] * xw[j]; }
  float gamma = 2.0f / fmaxf(1.0f - x2n, 1e-15f);
#pragma unroll
  for (int c = 0; c < DIM; c++) GT[g_tile_idx(c, n)] = f2bf(gamma * xw[c]);
  GT[g_tile_idx(32, n)] = f2bf(gamma - 1.0f);
  GT[g_tile_idx(33, n)] = f2bf(1.0f);
#pragma unroll
  for (int c = DIM + 2; c < 48; c++) GT[g_tile_idx(c, n)] = 0;
}

__global__ void k_pre1(const float* __restrict__ X, const float* __restrict__ W,
                       unsigned short* __restrict__ GT) {
  __shared__ float Wl[DIM * DIM];
  for (int i = threadIdx.x; i < DIM * DIM; i += blockDim.x) Wl[i] = W[i];
  __syncthreads();
  const int n = blockIdx.x * blockDim.x + threadIdx.x;
  float x[DIM];
#pragma unroll
  for (int i = 0; i < DIM; i += 4) {
    float4 v = *(const float4*)(X + (size_t)n * DIM + i);
    x[i] = v.x; x[i + 1] = v.y; x[i + 2] = v.z; x[i + 3] = v.w;
  }
  pre_math(Wl, x, GT, n);
}

// ---------------- parallel split-reduce (4 subs x 2 splits) + post tail ----------------
// block = 256 threads = 64 n x 4 subs; deterministic combine order.
__device__ inline void par_reduce(const float* __restrict__ Cpart, int n, int sub, int nl,
                                  float red[4][64][NCOLC]) {
  float acc[NCOLC];
#pragma unroll
  for (int c = 0; c < NCOLC; c++) acc[c] = 0.f;
#pragma unroll
  for (int si = 0; si < 2; si++) {
    const int s = sub * 2 + si;
    const float4* p = (const float4*)(Cpart + ((size_t)s * N_NODES + n) * NCOLC);
#pragma unroll
    for (int qq = 0; qq < NCOLC / 4; qq++) {
      float4 v = p[qq];
      acc[qq * 4 + 0] += v.x; acc[qq * 4 + 1] += v.y;
      acc[qq * 4 + 2] += v.z; acc[qq * 4 + 3] += v.w;
    }
  }
#pragma unroll
  for (int c = 0; c < NCOLC; c++) red[sub][nl][c] = acc[c];
}

__device__ inline void post_tail(const float acc[NCOLC], float xo[DIM]) {
  float denom = acc[32];
  float alpha = acc[33];
  denom = (denom >= 0.f) ? fmaxf(denom, 1e-10f) : fminf(denom, -1e-10f);
  float inv = 1.0f / denom;
  float v[DIM];
  float vn2 = 0.f;
#pragma unroll
  for (int c = 0; c < DIM; c++) { v[c] = acc[c] * inv; vn2 += v[c] * v[c]; }
  float vn = sqrtf(fmaxf(vn2, 1e-30f));
  float un = alpha * 0.5f * artanh_pos(vn);
  float su = un / vn;
  float r[DIM];
  float rn2 = 0.f;
#pragma unroll
  for (int c = 0; c < DIM; c++) { r[c] = fmaxf(su * v[c], 0.f); rn2 += r[c] * r[c]; }
  float rn = sqrtf(fmaxf(rn2, 1e-30f));
  float so = tanhf(rn) / rn;
#pragma unroll
  for (int c = 0; c < DIM; c++) xo[c] = so * r[c];
}

__global__ __launch_bounds__(256) void k_postpre(const float* __restrict__ Cpart,
                                                 const float* __restrict__ W,
                                                 unsigned short* __restrict__ GT) {
  __shared__ float Wl[DIM * DIM];
  __shared__ float red[4][64][NCOLC];
  const int t = threadIdx.x;
  const int nl = t & 63;
  const int sub = t >> 6;
  for (int i = t; i < DIM * DIM; i += 256) Wl[i] = W[i];
  const int n = blockIdx.x * 64 + nl;
  par_reduce(Cpart, n, sub, nl, red);
  __syncthreads();
  if (sub == 0) {
    float acc[NCOLC];
#pragma unroll
    for (int c = 0; c < NCOLC; c++)
      acc[c] = ((red[0][nl][c] + red[1][nl][c]) + red[2][nl][c]) + red[3][nl][c];
    float x[DIM];
    post_tail(acc, x);
    pre_math(Wl, x, GT, n);
  }
}

__global__ __launch_bounds__(256) void k_postlogits(const float* __restrict__ Cpart,
                                                    const float* __restrict__ Wl_g,
                                                    const float* __restrict__ B_g,
                                                    unsigned short* __restrict__ LT) {
  __shared__ float Wc[DIM * NCLS];
  __shared__ float Bc[NCLS * DIM];
  __shared__ float an_s[NCLS], lam_s[NCLS], b2_s[NCLS];
  __shared__ float red[4][64][NCOLC];
  const int t = threadIdx.x;
  const int nl = t & 63;
  const int sub = t >> 6;
  for (int i = t; i < DIM * NCLS; i += 256) { Wc[i] = Wl_g[i]; Bc[i] = B_g[i]; }
  __syncthreads();
  if (t < NCLS) {
    int c = t;
    float b2 = 0.f, w2 = 0.f;
    for (int d = 0; d < DIM; d++) {
      b2 += Bc[c * DIM + d] * Bc[c * DIM + d];
      w2 += Wc[d * NCLS + c] * Wc[d * NCLS + c];
    }
    b2_s[c] = b2;
    an_s[c] = fmaxf(sqrtf(w2), 1e-10f);
    lam_s[c] = 2.0f / fmaxf(1.0f - b2, 1e-15f);
  }
  const int n = blockIdx.x * 64 + nl;
  par_reduce(Cpart, n, sub, nl, red);
  __syncthreads();
  if (sub == 0) {
    float acc[NCOLC];
#pragma unroll
    for (int c = 0; c < NCOLC; c++)
      acc[c] = ((red[0][nl][c] + red[1][nl][c]) + red[2][nl][c]) + red[3][nl][c];
    float x[DIM];
    post_tail(acc, x);
    float y2 = 0.f;
#pragma unroll
    for (int i = 0; i < DIM; i++) y2 += x[i] * x[i];
    for (int c = 0; c < NCLS; c++) {
      float b2 = b2_s[c];
      float bx = 0.f;
      for (int d = 0; d < DIM; d++) bx += Bc[c * DIM + d] * x[d];
      float xy = -bx;
      float f1 = 1.0f + 2.0f * xy + y2;
      float f2 = 1.0f - b2;
      float den = fmaxf(1.0f + 2.0f * xy + b2 * y2, 1e-15f);
      float invden = 1.0f / den;
      float zn2 = 0.f, za = 0.f;
      for (int d = 0; d < DIM; d++) {
        float z = (f1 * (-Bc[c * DIM + d]) + f2 * x[d]) * invden;
        zn2 += z * z;
        za += z * Wc[d * NCLS + c];
      }
      float zn = fmaxf(sqrtf(fmaxf(zn2, 1e-30f)), 1e-10f);
      float dist = asinhf(2.0f * za / ((1.0f - zn * zn) * an_s[c]));
      LT[l_tile_idx(c, n)] = f2bf(lam_s[c] * an_s[c] * dist);
    }
  }
}

// ---------------- MFMA matmul over Abf tiles (passes 2/3), 1024-k per block ----------------
template <int NF>
__global__ __launch_bounds__(256) void k_mm(const unsigned short* __restrict__ A,
                                            const unsigned short* __restrict__ BT,
                                            float* __restrict__ Cpart) {
  const int lane = threadIdx.x & 63;
  const int wid = threadIdx.x >> 6;
  const int r0 = blockIdx.x * 128 + wid * 32;
  const int kt0 = blockIdx.y * 32;
  const int lr = lane & 15;
  const int lkg = lane >> 4;
  const int poff = lr * 32 + lkg * 8;
  const int BS = (NF == 3) ? 3 : 1;
  f32x4 acc[2][NF];
#pragma unroll
  for (int m = 0; m < 2; m++)
#pragma unroll
    for (int nf = 0; nf < NF; nf++) acc[m][nf] = (f32x4){0.f, 0.f, 0.f, 0.f};
  const unsigned short* pa0 = A + ((size_t)(r0 >> 4) * NKT + kt0) * 512 + poff;
  const unsigned short* pa1 = pa0 + RT_STRIDE;
  const unsigned short* pbB = BT + (size_t)kt0 * BS * 512 + poff;
#pragma unroll 4
  for (int kt = 0; kt < 32; kt++) {
    bf16x8 a0 = *(const bf16x8*)(pa0 + (size_t)kt * 512);
    bf16x8 a1 = *(const bf16x8*)(pa1 + (size_t)kt * 512);
#pragma unroll
    for (int nf = 0; nf < NF; nf++) {
      bf16x8 b = *(const bf16x8*)(pbB + (size_t)(kt * BS + nf) * 512);
      acc[0][nf] = __builtin_amdgcn_mfma_f32_16x16x32_bf16(a0, b, acc[0][nf], 0, 0, 0);
      acc[1][nf] = __builtin_amdgcn_mfma_f32_16x16x32_bf16(a1, b, acc[1][nf], 0, 0, 0);
    }
  }
  const int NCOL = (NF == 3) ? NCOLC : NF * 16;
  float* Cb = Cpart + (size_t)blockIdx.y * N_NODES * NCOL;
#pragma unroll
  for (int m = 0; m < 2; m++)
#pragma unroll
    for (int nf = 0; nf < NF; nf++) {
      if (NF == 3 && nf == 2 && lr >= 4) continue;
#pragma unroll
      for (int j = 0; j < 4; j++) {
        int row = r0 + m * 16 + lkg * 4 + j;
        int col = nf * 16 + lr;
        Cb[(size_t)row * NCOL + col] = acc[m][nf][j];
      }
    }
}

// ---------------- final splitK reduce into d_out ----------------
template <int TOTAL>
__global__ void k_red(const float* __restrict__ part, float* __restrict__ outb) {
  int i = blockIdx.x * blockDim.x + threadIdx.x;
  if (i < TOTAL) {
    float s = 0.f;
#pragma unroll
    for (int qq = 0; qq < SPLITS; qq++) s += part[(size_t)qq * TOTAL + i];
    outb[i] = s;
  }
}

extern "C" void kernel_launch(void* const* d_in, const int* in_sizes, int n_in,
                              void* d_out, int out_size, void* d_ws, size_t ws_size,
                              hipStream_t stream) {
  (void)in_sizes; (void)n_in; (void)out_size; (void)ws_size;
  const float* X  = (const float*)d_in[0];
  const float* A  = (const float*)d_in[1];
  const float* W1 = (const float*)d_in[2];
  const float* W2 = (const float*)d_in[3];
  const float* WL = (const float*)d_in[4];
  const float* PK = (const float*)d_in[5];
  float* out = (float*)d_out;

  char* ws = (char*)d_ws;
  unsigned short* Abf = (unsigned short*)ws;                  // 134,217,728 B (tiled)
  unsigned short* GT  = (unsigned short*)(ws + 134217728);    //     786,432 B (tiled)
  float* Cpart        = (float*)(ws + 135004160);             //   9,437,184 B (8 splits)
  unsigned short* LT  = (unsigned short*)(ws + 153878528);    //     262,144 B (tiled)

  // layer 1: fused pipelined convert + mm1 (NT loads for A, NT stores for Abf)
  k_pre1<<<N_NODES / 64, 64, 0, stream>>>(X, W1, GT);
  k_mmc<<<4096, 256, 0, stream>>>(A, GT, Abf, Cpart);
  k_postpre<<<N_NODES / 64, 256, 0, stream>>>(Cpart, W2, GT);

  // layer 2
  k_mm<3><<<dim3(64, 8), 256, 0, stream>>>(Abf, GT, Cpart);
  k_postlogits<<<N_NODES / 64, 256, 0, stream>>>(Cpart, WL, PK, LT);

  // logits aggregation
  k_mm<1><<<dim3(64, 8), 256, 0, stream>>>(Abf, LT, Cpart);
  k_red<N_NODES * NCLS><<<(N_NODES * NCLS + 255) / 256, 256, 0, stream>>>(Cpart, out);
}